// Round 5
// baseline (297.600 us; speedup 1.0000x reference)
//
#include <hip/hip_runtime.h>

#define NN   50000
#define NE   800000
#define INF  128
#define EF   32
#define OUTF 128
#define KDIM 288   // 128 (h) + 160 (mean_h|mean_e)
#define NBLK ((NN + 1023) / 1024)   // 49 scan blocks
#define CVT_BLKS 3125               // NN*INF/2048 exactly
#define LDS_STRIDE 184              // elems; 368 B rows: 16B-aligned, <=2-way banks

typedef __attribute__((ext_vector_type(8))) short     short8;   // 8 bf16
typedef __attribute__((ext_vector_type(8))) unsigned short ushort8;
typedef __attribute__((ext_vector_type(4))) float     float4v;
typedef __attribute__((ext_vector_type(2))) float     float2v;

__device__ __forceinline__ unsigned short f2bf(float f) {
    union { float f; unsigned int u; } c; c.f = f;
    const unsigned int r = (c.u + 0x7FFFu + ((c.u >> 16) & 1u)) >> 16;
    return (unsigned short)r;
}

// ---------------------------------------------------------------------------
// Fused prep+pack: build Mb[kb(9)][ct(8)][lane(64)][8] bf16 directly.
//   M[k][j]      = W_w[j][k]                                (k < 128)
//   M[128+m][j]  = sum_c weight[m][c] * W_w[j][128+c]       (m in [0,160))
// B-frag layout for mfma_f32_16x16x32_bf16: col=ct*16+(lane&15),
// k0 = kb*32 + (lane>>4)*8. grid = 72 blocks x 64 threads.
// ---------------------------------------------------------------------------
__global__ void pack_kernel(const float* __restrict__ weight,
                            const float* __restrict__ W_w,
                            unsigned short* __restrict__ Mb) {
    __shared__ float wrow[32][129];   // weight rows for this kb
    __shared__ float wcol[16][129];   // W_w[col][128+c] for this ct
    const int b = blockIdx.x;          // kb*8 + ct
    const int kb = b >> 3;
    const int ct = b & 7;
    const int lane = threadIdx.x;
    const int colLoc = lane & 15;
    const int quad = lane >> 4;
    const int col = ct * 16 + colLoc;

    ushort8 v;
    if (kb < 4) {
        const int k0 = kb * 32 + quad * 8;
        const float4 p0 = *(const float4*)(W_w + (size_t)col * 256 + k0);
        const float4 p1 = *(const float4*)(W_w + (size_t)col * 256 + k0 + 4);
        v[0] = f2bf(p0.x); v[1] = f2bf(p0.y); v[2] = f2bf(p0.z); v[3] = f2bf(p0.w);
        v[4] = f2bf(p1.x); v[5] = f2bf(p1.y); v[6] = f2bf(p1.z); v[7] = f2bf(p1.w);
    } else {
        const int m0 = (kb - 4) * 32;  // block's first weight row
        for (int idx = lane; idx < 32 * 128; idx += 64)
            wrow[idx >> 7][idx & 127] =
                weight[(size_t)(m0 + (idx >> 7)) * 128 + (idx & 127)];
        for (int idx = lane; idx < 16 * 128; idx += 64)
            wcol[idx >> 7][idx & 127] =
                W_w[(size_t)(ct * 16 + (idx >> 7)) * 256 + 128 + (idx & 127)];
        __syncthreads();
        float acc[8] = {};
        for (int c = 0; c < 128; ++c) {
            const float wc = wcol[colLoc][c];
#pragma unroll
            for (int i = 0; i < 8; ++i)
                acc[i] += wrow[quad * 8 + i][c] * wc;
        }
#pragma unroll
        for (int i = 0; i < 8; ++i) v[i] = f2bf(acc[i]);
    }
    *(ushort8*)(Mb + ((size_t)(b * 64 + lane) * 8)) = v;
}

// ---------------------------------------------------------------------------
// Fused: h fp32->bf16 table (+ zero row NN) and dst histogram.
// Histogram's atomicAdd return value IS the edge's rank within its dst
// bucket -> stored to rank[] so the later scatter needs no atomics.
// Role split by blockIdx: [0,3125)=cvt, 3125=zero row, (3125,..]=hist.
// ---------------------------------------------------------------------------
__global__ __launch_bounds__(256)
void cvt_hist_kernel(const float* __restrict__ h,
                     unsigned short* __restrict__ hb,
                     const int* __restrict__ dst,
                     int* __restrict__ off,
                     int* __restrict__ rank) {
    const int b = blockIdx.x;
    if (b < CVT_BLKS) {
        const size_t i = (size_t)(b * 256 + threadIdx.x) * 8;
        const float4 a0 = *(const float4*)(h + i);
        const float4 a1 = *(const float4*)(h + i + 4);
        ushort8 v;
        v[0] = f2bf(a0.x); v[1] = f2bf(a0.y); v[2] = f2bf(a0.z); v[3] = f2bf(a0.w);
        v[4] = f2bf(a1.x); v[5] = f2bf(a1.y); v[6] = f2bf(a1.z); v[7] = f2bf(a1.w);
        *(ushort8*)(hb + i) = v;
        return;
    }
    if (b == CVT_BLKS) {
        // zero row NN (target for masked-off edge slots in gather)
        if (threadIdx.x < 16) {
            ushort8 z = {};
            *(ushort8*)(hb + (size_t)NN * INF + threadIdx.x * 8) = z;
        }
        return;
    }
    const int e = ((b - CVT_BLKS - 1) * 256 + threadIdx.x) * 4;
    if (e < NE) {
        const int4 d = *(const int4*)(dst + e);
        int4 r;
        r.x = atomicAdd(&off[d.x], 1);
        r.y = atomicAdd(&off[d.y], 1);
        r.z = atomicAdd(&off[d.z], 1);
        r.w = atomicAdd(&off[d.w], 1);
        *(int4*)(rank + e) = r;
    }
}

// ---------------------------------------------------------------------------
// Scan phase 1: per-block (1024 elems) sum -> partial[b]
// ---------------------------------------------------------------------------
__global__ __launch_bounds__(256)
void scan1_kernel(const int* __restrict__ off, int* __restrict__ partial) {
    const int b = blockIdx.x;
    const int tid = threadIdx.x;
    const int idx = b * 1024 + tid * 4;
    int v0 = 0, v1 = 0, v2 = 0, v3 = 0;
    if (idx + 3 < NN) {
        const int4 q = *(const int4*)(off + idx);
        v0 = q.x; v1 = q.y; v2 = q.z; v3 = q.w;
    } else {
        if (idx + 0 < NN) v0 = off[idx + 0];
        if (idx + 1 < NN) v1 = off[idx + 1];
        if (idx + 2 < NN) v2 = off[idx + 2];
    }
    int t = v0 + v1 + v2 + v3;
#pragma unroll
    for (int ofs = 32; ofs > 0; ofs >>= 1) t += __shfl_down(t, ofs);
    __shared__ int wsum[4];
    if ((tid & 63) == 0) wsum[tid >> 6] = t;
    __syncthreads();
    if (tid == 0) partial[b] = wsum[0] + wsum[1] + wsum[2] + wsum[3];
}

// ---------------------------------------------------------------------------
// Scan phase 2+3 fused: every block re-scans the 49 partials in one wave,
// then does its local exclusive scan + in-place rewrite of off to EXCLUSIVE
// START offsets. off[NN] = NE sentinel. Scatter does not mutate off.
// ---------------------------------------------------------------------------
__global__ __launch_bounds__(256)
void scan3_kernel(int* __restrict__ off, const int* __restrict__ partial) {
    __shared__ int blockbase;
    __shared__ int wsum[4];
    const int b = blockIdx.x;
    const int tid = threadIdx.x;
    const int lane = tid & 63;
    const int wid = tid >> 6;

    if (b == 0 && tid == 0) off[NN] = NE;   // sentinel end offset

    if (wid == 0) {
        const int v = (lane < NBLK) ? partial[lane] : 0;
        int x = v;
#pragma unroll
        for (int ofs = 1; ofs < 64; ofs <<= 1) {
            const int t = __shfl_up(x, ofs);
            if (lane >= ofs) x += t;
        }
        if (lane == b) blockbase = x - v;   // exclusive prefix of this block
    }

    const int idx = b * 1024 + tid * 4;
    int v0 = 0, v1 = 0, v2 = 0, v3 = 0;
    if (idx + 3 < NN) {
        const int4 q = *(const int4*)(off + idx);
        v0 = q.x; v1 = q.y; v2 = q.z; v3 = q.w;
    } else {
        if (idx + 0 < NN) v0 = off[idx + 0];
        if (idx + 1 < NN) v1 = off[idx + 1];
        if (idx + 2 < NN) v2 = off[idx + 2];
    }
    const int tsum = v0 + v1 + v2 + v3;
    int x = tsum;
#pragma unroll
    for (int ofs = 1; ofs < 64; ofs <<= 1) {
        const int t = __shfl_up(x, ofs);
        if (lane >= ofs) x += t;
    }
    if (lane == 63) wsum[wid] = x;
    __syncthreads();
    int wp = 0;
    for (int w = 0; w < wid; ++w) wp += wsum[w];
    const int base = blockbase + wp + (x - tsum);
    if (idx + 0 < NN) off[idx + 0] = base;
    if (idx + 1 < NN) off[idx + 1] = base + v0;
    if (idx + 2 < NN) off[idx + 2] = base + v0 + v1;
    if (idx + 3 < NN) off[idx + 3] = base + v0 + v1 + v2;
}

// ---------------------------------------------------------------------------
// CSR build step 3: ATOMIC-FREE scatter. pos = off[d] + rank[e]; the four
// stores per thread are fully independent (no RMW round-trip chains).
// ---------------------------------------------------------------------------
__global__ __launch_bounds__(256)
void scatter_ids_kernel(const int* __restrict__ srcv,
                        const int* __restrict__ dst,
                        const int* __restrict__ off,    // start offsets
                        const int* __restrict__ rank,
                        int2* __restrict__ eo2) {
    const int e = (blockIdx.x * 256 + threadIdx.x) * 4;
    if (e < NE) {
        const int4 s = *(const int4*)(srcv + e);
        const int4 d = *(const int4*)(dst + e);
        const int4 r = *(const int4*)(rank + e);
        eo2[off[d.x] + r.x] = make_int2(s.x, e + 0);
        eo2[off[d.y] + r.y] = make_int2(s.y, e + 1);
        eo2[off[d.z] + r.z] = make_int2(s.z, e + 2);
        eo2[off[d.w] + r.w] = make_int2(s.w, e + 3);
    }
}

// ---------------------------------------------------------------------------
// FUSED gather + node GEMM. Block = 256 thr = 4 waves, owns 16 nodes
// (NN = 3125*16 exactly -> grid 3125, no tail).
// Phase 1 (per wave, 4 nodes sequentially): identical edge loop as before
// (16-lane groups, 4 edges per dwordx4, ds_bpermute index distribution),
// but means land in LDS (16 x LDS_STRIDE bf16; cols 0..127 = mean_h,
// 128..159 = mean_e) instead of global memory.
// Phase 2 (after one barrier): wave w computes ct tiles {2w, 2w+1} for all
// 16 nodes: 9 kb x 2 MFMA. A-frag kb<4 from hb (block's own rows, L2-hot),
// kb>=4 from LDS. Epilogue adds W_b+bias directly (cvec eliminated).
// ---------------------------------------------------------------------------
__global__ __launch_bounds__(256)
void gather_gemm_kernel(const unsigned short* __restrict__ hb,
                        const float* __restrict__ eftr,
                        const int* __restrict__ off,   // start offsets, off[NN]=NE
                        const int2* __restrict__ eo2,
                        const unsigned short* __restrict__ Mb,
                        const float* __restrict__ W_b,
                        const float* __restrict__ bias,
                        float* __restrict__ out) {
    __shared__ unsigned short ldsA[16 * LDS_STRIDE];   // 5,888 B
    const int tid = threadIdx.x;
    const int lane = tid & 63;
    const int wid = tid >> 6;
    const int blk = blockIdx.x;

    const int ql = lane & 15;      // position within 16-lane group
    const int qg = lane >> 4;      // edge-slot group 0..3

    // ---- phase 1: gather means for this wave's 4 nodes into LDS ----
    for (int i = 0; i < 4; ++i) {
        const int nloc = wid * 4 + i;
        const int node = blk * 16 + nloc;
        const int start = off[node];
        const int end   = off[node + 1];

        float ax[8] = {0.f, 0.f, 0.f, 0.f, 0.f, 0.f, 0.f, 0.f};
        float aex = 0.f, aey = 0.f;

        for (int base = start; base < end; base += 64) {
            const int m = min(64, end - base);
            int px = 0, py = 0;
            if (lane < m) {
                const long long pv =
                    __builtin_nontemporal_load((const long long*)(eo2 + base + lane));
                px = (int)pv;
                py = (int)(pv >> 32);
            }
            for (int j = 0; j < m; j += 8) {
#pragma unroll
                for (int u = 0; u < 2; ++u) {
                    const int eidx = j + u * 4 + qg;      // my group's edge
                    const bool valid = eidx < m;
                    const int bidx = (eidx & 63) * 4;     // bpermute byte idx
                    int s = __builtin_amdgcn_ds_bpermute(bidx, px);
                    int e = __builtin_amdgcn_ds_bpermute(bidx, py);
                    s = valid ? s : NN;                    // zero row
                    e = valid ? e : 0;                     // hot row, masked

                    const uint4 hv = *(const uint4*)(hb + (size_t)s * INF + ql * 8);
#pragma unroll
                    for (int k = 0; k < 4; ++k) {
                        const unsigned w = (&hv.x)[k];
                        union { unsigned u; float f; } lo, hi;
                        lo.u = w << 16;
                        hi.u = w & 0xffff0000u;
                        ax[2 * k]     += lo.f;
                        ax[2 * k + 1] += hi.f;
                    }

                    const float2v ev = __builtin_nontemporal_load(
                        (const float2v*)(eftr + (size_t)e * EF + ql * 2));
                    aex += valid ? ev.x : 0.f;
                    aey += valid ? ev.y : 0.f;
                }
            }
        }

        // fold the 4 edge-slot groups: lanes differing in bits 4,5
#pragma unroll
        for (int k = 0; k < 8; ++k) {
            ax[k] += __shfl_xor(ax[k], 16);
            ax[k] += __shfl_xor(ax[k], 32);
        }
        aex += __shfl_xor(aex, 16); aex += __shfl_xor(aex, 32);
        aey += __shfl_xor(aey, 16); aey += __shfl_xor(aey, 32);

        if (qg == 0) {
            const float inv = 1.f / fmaxf((float)(end - start), 1.f);
            ushort8 mv;
#pragma unroll
            for (int k = 0; k < 8; ++k) mv[k] = f2bf(ax[k] * inv);
            *(ushort8*)(ldsA + nloc * LDS_STRIDE + ql * 8) = mv;
            const unsigned me =
                (unsigned)f2bf(aex * inv) | ((unsigned)f2bf(aey * inv) << 16);
            *(unsigned*)(ldsA + nloc * LDS_STRIDE + 128 + ql * 2) = me;
        }
    }
    __syncthreads();

    // ---- phase 2: GEMM for the block's 16 nodes, wave wid owns 2 ct ----
    const int m16 = lane & 15;
    const int quad = lane >> 4;
    const int koff = quad * 8;
    const int ct0 = wid * 2;

    float4v acc0 = {};
    float4v acc1 = {};

    for (int kb = 0; kb < 9; ++kb) {
        short8 a;
        if (kb < 4)
            a = *(const short8*)(const void*)(hb + (size_t)(blk * 16 + m16) * INF +
                                              kb * 32 + koff);
        else
            a = *(const short8*)(const void*)(ldsA + m16 * LDS_STRIDE +
                                              (kb - 4) * 32 + koff);
        const short8* bp = (const short8*)(Mb + (size_t)kb * 8 * 64 * 8);
        const short8 b0 = bp[ct0 * 64 + lane];
        const short8 b1 = bp[(ct0 + 1) * 64 + lane];
        acc0 = __builtin_amdgcn_mfma_f32_16x16x32_bf16(a, b0, acc0, 0, 0, 0);
        acc1 = __builtin_amdgcn_mfma_f32_16x16x32_bf16(a, b1, acc1, 0, 0, 0);
    }

    const int c0 = ct0 * 16 + m16;
    const int c1 = c0 + 16;
    const float cv0 = W_b[c0] + bias[c0];
    const float cv1 = W_b[c1] + bias[c1];

#pragma unroll
    for (int r = 0; r < 4; ++r) {
        const int row = blk * 16 + quad * 4 + r;
        float* orow = out + (size_t)row * OUTF;
        __builtin_nontemporal_store(acc0[r] + cv0, &orow[c0]);
        __builtin_nontemporal_store(acc1[r] + cv1, &orow[c1]);
    }
}

extern "C" void kernel_launch(void* const* d_in, const int* in_sizes, int n_in,
                              void* d_out, int out_size, void* d_ws, size_t ws_size,
                              hipStream_t stream) {
    const float* h      = (const float*)d_in[0];
    const float* eftr   = (const float*)d_in[1];
    const float* weight = (const float*)d_in[2];
    const float* W_w    = (const float*)d_in[3];
    const float* W_b    = (const float*)d_in[4];
    const float* bias   = (const float*)d_in[5];
    const int*   src    = (const int*)d_in[6];
    const int*   dst    = (const int*)d_in[7];
    float* out = (float*)d_out;

    // workspace layout (byte offsets):
    char* base = (char*)d_ws;
    unsigned short* h_bf = (unsigned short*)(base);                  // (NN+1)*128 bf16 = 12,800,256
    unsigned short* Mb   = (unsigned short*)(base + 12800512);       // 73,728
    int*   off           = (int*)(base + 12874752);                  // (NN+1) int = 200,004
    int2*  eo2           = (int2*)(base + 13075456);                 // NE int2 = 6,400,000
    int*   rank          = (int*)(base + 19475456);                  // NE int = 3,200,000
    int*   partial       = (int*)(base + 22675456);                  // NBLK int
    // total ≈ 22.7 MB

    hipMemsetAsync(off, 0, (size_t)NN * sizeof(int), stream);

    pack_kernel<<<72, 64, 0, stream>>>(weight, W_w, Mb);
    cvt_hist_kernel<<<CVT_BLKS + 1 + (NE / 4 + 255) / 256, 256, 0, stream>>>(
        h, h_bf, dst, off, rank);
    scan1_kernel<<<NBLK, 256, 0, stream>>>(off, partial);
    scan3_kernel<<<NBLK, 256, 0, stream>>>(off, partial);
    scatter_ids_kernel<<<(NE / 4 + 255) / 256, 256, 0, stream>>>(src, dst, off,
                                                                 rank, eo2);
    gather_gemm_kernel<<<NN / 16, 256, 0, stream>>>(h_bf, eftr, off, eo2,
                                                    Mb, W_b, bias, out);
}